// Round 12
// baseline (410.710 us; speedup 1.0000x reference)
//
#include <hip/hip_runtime.h>
#include <math.h>

#define NBATCH 16
#define DDIM   256
#define TLEN   1500
#define NROWS  (NBATCH * TLEN)     // 24000
#define KBINS  1024
#define NQ     8
#define RPB    32                  // rows per block
#define QMAX   512

typedef float f32x4 __attribute__((ext_vector_type(4)));
typedef int   i32x4 __attribute__((ext_vector_type(4)));
union FragI { uint4 u; i32x4 i; };

// LDS-only barrier: waits ds ops, does NOT drain vmcnt -> global prefetch
// stays in flight across phase boundaries. All inter-wave comms here are LDS.
__device__ __forceinline__ void barrier_lds() {
    __builtin_amdgcn_sched_barrier(0);
    asm volatile("s_waitcnt lgkmcnt(0)" ::: "memory");
    __builtin_amdgcn_s_barrier();
    __builtin_amdgcn_sched_barrier(0);
}

// quantize 4 floats to 4 i8 (round-nearest-even), accumulate exact eps^2
__device__ __forceinline__ unsigned pack8(float4 v, float inv, float s, float& e2) {
    float q0 = rintf(v.x * inv), q1 = rintf(v.y * inv);
    float q2 = rintf(v.z * inv), q3 = rintf(v.w * inv);
    float e0 = __builtin_fmaf(-s, q0, v.x), e1 = __builtin_fmaf(-s, q1, v.y);
    float f2 = __builtin_fmaf(-s, q2, v.z), f3 = __builtin_fmaf(-s, q3, v.w);
    e2 += e0 * e0 + e1 * e1 + f2 * f2 + f3 * f3;
    return ((unsigned)((int)q0 & 255)) | (((unsigned)((int)q1 & 255)) << 8)
         | (((unsigned)((int)q2 & 255)) << 16) | (((unsigned)((int)q3 & 255)) << 24);
}

// ws layout (floats):
// [0..8191]      cbsq
// [8192..8207]   stage scalars: q*2+0 = maxabs(cb_q), q*2+1 = max||c||  (plain floats)
// [8208..8215]   loss[8]
// [8224..16415]  eps2col[8192]  (per-col quant eps^2, pure writes)
// [16416..24607] colmax[8192]   (per-col maxabs, pure writes)
// [24608..]      cbbf (131072 uint4 = 2MB)

// ---------------------------------------------------------------------------
// Kernel 1: per-col cbsq (numpy-pairwise) + per-col maxabs. Pure stores,
// NO global atomics. Also zeroes loss.
// ---------------------------------------------------------------------------
__global__ __launch_bounds__(256) void table_kernel(const float* __restrict__ cb,
                                                    float* __restrict__ ws) {
    const int k = blockIdx.x * 256 + threadIdx.x;      // 0..8191
    if (blockIdx.x == 0 && threadIdx.x < NQ) ws[8208 + threadIdx.x] = 0.f;
    if (k >= NQ * KBINS) return;
    const float* p = cb + (size_t)k * DDIM;
    // numpy-pairwise sum(c*c) -- EXACT structure as the passing kernel
    float total = 0.f;
    #pragma unroll
    for (int h = 0; h < 2; ++h) {
        const float* ph = p + h * 128;
        float r[8];
        #pragma unroll
        for (int j = 0; j < 8; ++j) { float v = ph[j]; r[j] = __fmul_rn(v, v); }
        for (int i = 8; i < 128; i += 8) {
            #pragma unroll
            for (int j = 0; j < 8; ++j) {
                float v = ph[i + j];
                r[j] = __fadd_rn(r[j], __fmul_rn(v, v));
            }
        }
        float s = __fadd_rn(__fadd_rn(__fadd_rn(r[0], r[1]), __fadd_rn(r[2], r[3])),
                            __fadd_rn(__fadd_rn(r[4], r[5]), __fadd_rn(r[6], r[7])));
        total = __fadd_rn(total, s);
    }
    ws[k] = total;
    float ma = 0.f;
    for (int i = 0; i < DDIM; i += 4) {
        float4 v = *(const float4*)(p + i);
        ma = fmaxf(ma, fmaxf(fmaxf(fabsf(v.x), fabsf(v.y)), fmaxf(fabsf(v.z), fabsf(v.w))));
    }
    ws[16416 + k] = ma;
}

// ---------------------------------------------------------------------------
// Kernel 1a: per-stage scalars (maxabs, max||c||) via shuffle+LDS reduce.
// One block per stage; single plain store; NO contended atomics.
// ---------------------------------------------------------------------------
__global__ __launch_bounds__(256) void stagered_kernel(float* __restrict__ ws) {
    const int q = blockIdx.x;
    const int tid = threadIdx.x, l = tid & 63, w = tid >> 6;
    __shared__ float redm[4], redc[4];
    float ma = 0.f, cs = 0.f;
    for (int j = tid; j < KBINS; j += 256) {
        ma = fmaxf(ma, ws[16416 + q * KBINS + j]);
        cs = fmaxf(cs, ws[q * KBINS + j]);
    }
    #pragma unroll
    for (int d = 1; d < 64; d <<= 1) {
        ma = fmaxf(ma, __shfl_xor(ma, d, 64));
        cs = fmaxf(cs, __shfl_xor(cs, d, 64));
    }
    if (l == 0) { redm[w] = ma; redc[w] = cs; }
    __syncthreads();
    if (tid == 0) {
        ws[8192 + 2 * q]     = fmaxf(fmaxf(redm[0], redm[1]), fmaxf(redm[2], redm[3]));
        ws[8192 + 2 * q + 1] = sqrtf(fmaxf(fmaxf(redc[0], redc[1]), fmaxf(redc[2], redc[3])));
    }
}

// ---------------------------------------------------------------------------
// Kernel 1b: pre-quantize codebooks fp32 -> i8 (per-stage GLOBAL scale sBq)
// in per-lane MFMA fragment order; per-col eps^2 combined via shfl_xor +
// 16-slot LDS (one block = one (q,ch,w) tile, 4 waves = 4 ks) -> pure store.
// uint4 index J = ((((q*16+ch)*4 + w)*4 + ks)*64 + l); byte p of lane l:
// col = ch*64 + w*16 + (l&15), k = ks*64 + (l>>4)*16 + p  (A uses same k map)
// ---------------------------------------------------------------------------
__global__ __launch_bounds__(256) void precvt8_kernel(const float* __restrict__ cb,
                                                      float* __restrict__ ws,
                                                      uint4* __restrict__ cbbf) {
    __shared__ float e2c[16];
    const int j = blockIdx.x * 256 + threadIdx.x;      // < 131072
    const int l  = j & 63;
    const int ks = (j >> 6) & 3;
    const int w  = (j >> 8) & 3;
    const int ch = (j >> 10) & 15;
    const int q  = j >> 14;
    const int C  = ch * 64 + w * 16 + (l & 15);
    const int g  = l >> 4;
    if (threadIdx.x < 16) e2c[threadIdx.x] = 0.f;
    __syncthreads();
    const float* src = cb + ((size_t)q * KBINS + C) * DDIM + ks * 64 + g * 16;
    const float sB = fmaxf(ws[8192 + 2 * q], 1e-30f) * (1.f / 127.f);
    const float invB = 1.f / sB;
    float e2 = 0.f;
    uint4 o;
    o.x = pack8(*(const float4*)(src + 0),  invB, sB, e2);
    o.y = pack8(*(const float4*)(src + 4),  invB, sB, e2);
    o.z = pack8(*(const float4*)(src + 8),  invB, sB, e2);
    o.w = pack8(*(const float4*)(src + 12), invB, sB, e2);
    cbbf[j] = o;
    e2 += __shfl_xor(e2, 16, 64);
    e2 += __shfl_xor(e2, 32, 64);
    if (l < 16) atomicAdd(&e2c[l], e2);                // LDS atomic, 4 waves only
    __syncthreads();
    if (threadIdx.x < 16)
        ws[8224 + q * KBINS + ch * 64 + w * 16 + threadIdx.x] = e2c[threadIdx.x];
}

// ---------------------------------------------------------------------------
// Kernel 2: residual VQ. i8-MFMA screening, barrier-free monotone cross-wave
// Mpart thresholds (r11, measured-safe), PLUS per-block/wave ROTATED chunk
// order: base = hash(block,w); chunks processed (base*2 + i) mod 16. Any
// rotation is selection-safe (true winner passes at every threshold
// maturity; superset + overflow->repair). Purpose: co-resident waves on a
// SIMD (same w, different blocks) start at different phases -> dependency
// stalls decorrelate -> issue slots fill instead of stalling together.
// (256,3): 84-reg cap, 3 blocks/CU, 750 blocks <= 768 slots = one round.
// ---------------------------------------------------------------------------
template<bool WSCB>
__global__ __launch_bounds__(256, 3)
void rvq_kernel(const float* __restrict__ x,
                const float* __restrict__ cb,
                const uint4* __restrict__ cbbf,
                const float* __restrict__ ws,
                float* __restrict__ loss,
                float* __restrict__ out) {
    __shared__ __align__(16) float As[RPB][260];       // residual fp32 (33.3KB)
    __shared__ float cbsqs[KBINS];                     // 4KB
    __shared__ uint4 af_lds[2][4][64];                 // A i8 fragments (8KB)
    __shared__ float rsq[RPB];
    __shared__ float ean2_s[RPB];                      // row quant eps^2
    __shared__ float Mpart[4][RPB];                    // per-wave RUNNING row max
    __shared__ float ebn2_lds[NQ];                     // stage max col eps^2
    __shared__ unsigned long long winner[RPB];
    __shared__ int   idxs[RPB];
    __shared__ int   qlist[QMAX];                      // 2KB
    __shared__ int   qcnt;
    __shared__ unsigned ovf;
    __shared__ unsigned sAg;                           // block max |residual| bits

    const int tid = threadIdx.x;
    const int bid = blockIdx.x;
    const int r0  = bid * RPB;
    const int w   = tid >> 6;          // wave 0..3
    const int l   = tid & 63;
    const int cl  = l & 15;
    const int g   = l >> 4;            // 0..3

    // per-block/wave chunk rotation: start chunk = base (0,2,..,14)
    const int base = (((bid & 7) + ((bid >> 3) & 7) + w) & 7) * 2;

    if (tid < RPB) { rsq[tid] = 0.f; ean2_s[tid] = 0.f; }
    if (tid == 0) sAg = 0u;
    barrier_lds();

    // ---- load x (B,D,T) transposed into As[row][d]; ||r||^2 and sAg ----
    {
        const int row = tid & 31, dg = tid >> 5;
        const int n = r0 + row, b = n / TLEN, t = n % TLEN;
        const float* xp = x + (size_t)b * (DDIM * TLEN) + t;
        float pr = 0.f, ma = 0.f;
        #pragma unroll
        for (int dd = 0; dd < DDIM; dd += 8) {
            float v = xp[(size_t)(dd + dg) * TLEN];
            As[row][dd + dg] = v;
            pr = __builtin_fmaf(v, v, pr);
            ma = fmaxf(ma, fabsf(v));
        }
        atomicAdd(&rsq[row], pr);
        #pragma unroll
        for (int d = 1; d < 64; d <<= 1) ma = fmaxf(ma, __shfl_xor(ma, d, 64));
        if (l == 0) atomicMax(&sAg, __float_as_uint(ma));
    }
    // ---- prologue: reduce eps2col -> per-stage max (waves own q, q+4) ----
    if constexpr (WSCB) {
        for (int qq = w; qq < NQ; qq += 4) {
            float m = 0.f;
            for (int j = l; j < KBINS; j += 64)
                m = fmaxf(m, ws[8224 + qq * KBINS + j]);
            #pragma unroll
            for (int d = 1; d < 64; d <<= 1) m = fmaxf(m, __shfl_xor(m, d, 64));
            if (l == 0) ebn2_lds[qq] = m;
        }
    }
    barrier_lds();

    float* codes_f = out + (size_t)NBATCH * DDIM * TLEN;

    uint4 bufA[4], bufB[4];
    float sBq_pf = fmaxf(ws[8192], 1e-30f) * (1.f / 127.f);

    // B-fragment loader: 4 coalesced dwordx4 per chunk (i8, K=64 each)
    auto loadB = [&](uint4 (&buf)[4], int q_, int ch_) {
        if constexpr (WSCB) {
            const uint4* p = cbbf + ((size_t)((q_ * 16 + ch_) * 4 + w) * 4) * 64 + l;
            #pragma unroll
            for (int ks = 0; ks < 4; ++ks) buf[ks] = p[ks * 64];
        } else {
            const int C = ch_ * 64 + w * 16 + cl;
            const float* cp = cb + ((size_t)q_ * KBINS + C) * DDIM;
            const float sB = sBq_pf;
            const float invB = 1.f / sB;
            float dmy = 0.f;
            #pragma unroll
            for (int ks = 0; ks < 4; ++ks) {
                const int d0 = ks * 64 + g * 16;
                buf[ks].x = pack8(*(const float4*)(cp + d0 + 0),  invB, sB, dmy);
                buf[ks].y = pack8(*(const float4*)(cp + d0 + 4),  invB, sB, dmy);
                buf[ks].z = pack8(*(const float4*)(cp + d0 + 8),  invB, sB, dmy);
                buf[ks].w = pack8(*(const float4*)(cp + d0 + 12), invB, sB, dmy);
            }
        }
    };

    loadB(bufA, 0, base);              // prologue: stage 0, rotated first chunk
    __builtin_amdgcn_sched_barrier(0);

    for (int q = 0; q < NQ; ++q) {
        const float* cbq = cb + (size_t)q * (KBINS * DDIM);

        // ---- per-stage scalars (plain-float reads) ----
        const float sBq = fmaxf(ws[8192 + 2 * q], 1e-30f) * (1.f / 127.f);
        sBq_pf = (q < NQ - 1) ? fmaxf(ws[8192 + 2 * (q + 1)], 1e-30f) * (1.f / 127.f) : sBq;
        const float cnM  = ws[8192 + 2 * q + 1];
        float ebnS;
        if constexpr (WSCB) ebnS = sqrtf(ebn2_lds[q]);
        else                ebnS = 8.f * sBq;          // analytic bound fallback
        const float maxA = fmaxf(__uint_as_float(sAg), 1e-30f);
        const float sA   = maxA * (1.f / 127.f);
        const float invA = 127.f / maxA;
        const float scg  = 2.f * sA * sBq;             // wave-uniform fold scale

        // exact fp32 score of (row,col) -> tournament key -> atomicMax winner
        auto exact_score = [&](int row, int col) {
            const float* cp = cbq + (size_t)col * DDIM;
            const float* ar = As[row];
            float dot = 0.f;
            #pragma unroll 16
            for (int d = 0; d < DDIM; d += 4) {
                float4 c4 = *(const float4*)(cp + d);
                float4 a4 = *(const float4*)(ar + d);
                dot = __builtin_fmaf(a4.x, c4.x, dot);
                dot = __builtin_fmaf(a4.y, c4.y, dot);
                dot = __builtin_fmaf(a4.z, c4.z, dot);
                dot = __builtin_fmaf(a4.w, c4.w, dot);
            }
            float sx = __fsub_rn(__fmul_rn(2.f, dot), cbsqs[col]);
            unsigned ub = __float_as_uint(sx);
            ub = (ub & 0x80000000u) ? ~ub : (ub | 0x80000000u);
            unsigned long long key = ((unsigned long long)ub << 10) | (unsigned)(1023 - col);
            atomicMax(&winner[row], key);
        };

        // ---- stage cbsq into LDS ----
        #pragma unroll
        for (int j = 0; j < 4; ++j)
            cbsqs[tid + j * 256] = ws[q * KBINS + tid + j * 256];

        // ---- A fragments: residual -> i8 into LDS, COOPERATIVE (2/thread) ----
        #pragma unroll
        for (int i = 0; i < 2; ++i) {
            const int f  = tid + 256 * i;              // 0..511
            const int fl = f & 63, fks = (f >> 6) & 3, fmt = f >> 8;
            const int row = fmt * 16 + (fl & 15), gg = fl >> 4;
            const float* ap = &As[row][fks * 64 + gg * 16];
            float e2 = 0.f;
            uint4 o;
            o.x = pack8(*(const float4*)(ap + 0),  invA, sA, e2);
            o.y = pack8(*(const float4*)(ap + 4),  invA, sA, e2);
            o.z = pack8(*(const float4*)(ap + 8),  invA, sA, e2);
            o.w = pack8(*(const float4*)(ap + 12), invA, sA, e2);
            af_lds[fmt][fks][fl] = o;
            atomicAdd(&ean2_s[row], e2);
        }

        if (tid < RPB) winner[tid] = 0ull;
        if (tid < 4 * RPB) ((float*)Mpart)[tid] = -INFINITY;
        if (tid == 0) { qcnt = 0; ovf = 0u; }
        barrier_lds();   // ean2/rsq complete; Mpart init + winner visible

        // ---- per-lane margins (registers; rsq/ean2_s stable post-barrier) ----
        float marg[2][4];
        #pragma unroll
        for (int mt = 0; mt < 2; ++mt)
            #pragma unroll
            for (int jj = 0; jj < 4; ++jj) {
                const int r = mt * 16 + g * 4 + jj;
                marg[mt][jj] = __builtin_fmaf(sqrtf(rsq[r]), ebnS,
                                              sqrtf(ean2_s[r]) * cnM) + 0.25f;
            }

        // ---- BARRIER-FREE screen, ROTATED chunk order (base + i) mod 16 ----
        for (int gi = 0; gi < 8; ++gi) {
            float m_lane[2][4];
            #pragma unroll
            for (int mt = 0; mt < 2; ++mt)
                #pragma unroll
                for (int r = 0; r < 4; ++r) m_lane[mt][r] = -INFINITY;
            unsigned spack[2][2][2];   // 8 VGPRs, static-indexed

            #pragma unroll
            for (int cc = 0; cc < 2; ++cc) {
                const int i  = gi * 2 + cc;
                const int ch = (base + i) & 15;
                uint4 (&cur)[4] = (cc & 1) ? bufB : bufA;
                uint4 (&nxt)[4] = (cc & 1) ? bufA : bufB;

                // prefetch next chunk in rotated order (wraps to next stage)
                int pq = q, pch = (base + i + 1) & 15;
                if (i == 15) { pq = (q < NQ - 1) ? q + 1 : q; pch = base; }
                loadB(nxt, pq, pch);
                __builtin_amdgcn_sched_barrier(0);   // pin: loads issue BEFORE MFMAs

                // 8 MFMAs; A streamed from LDS (stride-16B b128)
                i32x4 a0 = {0, 0, 0, 0}, a1 = {0, 0, 0, 0};
                #pragma unroll
                for (int ks = 0; ks < 4; ++ks) {
                    FragI fa0, fa1, b;
                    fa0.u = af_lds[0][ks][l];
                    fa1.u = af_lds[1][ks][l];
                    b.u = cur[ks];
                    a0 = __builtin_amdgcn_mfma_i32_16x16x64_i8(fa0.i, b.i, a0, 0, 0, 0);
                    a1 = __builtin_amdgcn_mfma_i32_16x16x64_i8(fa1.i, b.i, a1, 0, 0, 0);
                }

                // fold: s = scg*idot - cbsq; running max; truncate-pack
                const float cq = cbsqs[ch * 64 + w * 16 + cl];
                {
                    float s0 = __builtin_fmaf(scg, (float)a0[0], -cq);
                    float s1 = __builtin_fmaf(scg, (float)a0[1], -cq);
                    float s2 = __builtin_fmaf(scg, (float)a0[2], -cq);
                    float s3 = __builtin_fmaf(scg, (float)a0[3], -cq);
                    m_lane[0][0] = fmaxf(m_lane[0][0], s0);
                    m_lane[0][1] = fmaxf(m_lane[0][1], s1);
                    m_lane[0][2] = fmaxf(m_lane[0][2], s2);
                    m_lane[0][3] = fmaxf(m_lane[0][3], s3);
                    spack[cc][0][0] = (__float_as_uint(s1) & 0xFFFF0000u) | (__float_as_uint(s0) >> 16);
                    spack[cc][0][1] = (__float_as_uint(s3) & 0xFFFF0000u) | (__float_as_uint(s2) >> 16);
                }
                {
                    float s0 = __builtin_fmaf(scg, (float)a1[0], -cq);
                    float s1 = __builtin_fmaf(scg, (float)a1[1], -cq);
                    float s2 = __builtin_fmaf(scg, (float)a1[2], -cq);
                    float s3 = __builtin_fmaf(scg, (float)a1[3], -cq);
                    m_lane[1][0] = fmaxf(m_lane[1][0], s0);
                    m_lane[1][1] = fmaxf(m_lane[1][1], s1);
                    m_lane[1][2] = fmaxf(m_lane[1][2], s2);
                    m_lane[1][3] = fmaxf(m_lane[1][3], s3);
                    spack[cc][1][0] = (__float_as_uint(s1) & 0xFFFF0000u) | (__float_as_uint(s0) >> 16);
                    spack[cc][1][1] = (__float_as_uint(s3) & 0xFFFF0000u) | (__float_as_uint(s2) >> 16);
                }
            }

            // ---- reduce group maxima over the 16-col group (intra-wave) ----
            #pragma unroll
            for (int m = 1; m <= 8; m <<= 1)
                #pragma unroll
                for (int mt = 0; mt < 2; ++mt)
                    #pragma unroll
                    for (int r = 0; r < 4; ++r)
                        m_lane[mt][r] = fmaxf(m_lane[mt][r], __shfl_xor(m_lane[mt][r], m, 64));

            // ---- publish own wave's running max (monotone, no barrier) ----
            if (cl == 0) {
                #pragma unroll
                for (int mt = 0; mt < 2; ++mt)
                    #pragma unroll
                    for (int r = 0; r < 4; ++r) {
                        const int rr = mt * 16 + g * 4 + r;
                        Mpart[w][rr] = fmaxf(Mpart[w][rr], m_lane[mt][r]);
                    }
            }

            // ---- thresholds: racy cross-wave max (stale = lower bound, safe) ----
            float thrl[2][4];
            #pragma unroll
            for (int mt = 0; mt < 2; ++mt)
                #pragma unroll
                for (int jj = 0; jj < 4; ++jj) {
                    const int rr = mt * 16 + g * 4 + jj;
                    float Mr = fmaxf(fmaxf(Mpart[0][rr], Mpart[1][rr]),
                                     fmaxf(Mpart[2][rr], Mpart[3][rr]));
                    Mr = fmaxf(Mr, m_lane[mt][jj]);    // own group, provably current
                    thrl[mt][jj] = Mr - (marg[mt][jj] + 0.006f * fabsf(Mr));
                }

            // ---- scan the group's 2 chunks of packed scores ----
            #pragma unroll
            for (int cc = 0; cc < 2; ++cc) {
                const int ch = (base + gi * 2 + cc) & 15;
                const int colc = ch * 64 + w * 16 + cl;
                #pragma unroll
                for (int mt = 0; mt < 2; ++mt)
                    #pragma unroll
                    for (int pr = 0; pr < 2; ++pr) {
                        unsigned u = spack[cc][mt][pr];
                        float slo = __uint_as_float(u << 16);
                        float shi = __uint_as_float(u & 0xFFFF0000u);
                        if (slo >= thrl[mt][pr * 2]) {
                            const int row = mt * 16 + g * 4 + pr * 2;
                            int p = atomicAdd(&qcnt, 1);
                            if (__builtin_expect(p < QMAX, 1)) qlist[p] = (row << 10) | colc;
                            else atomicOr(&ovf, 1u << row);
                        }
                        if (shi >= thrl[mt][pr * 2 + 1]) {
                            const int row = mt * 16 + g * 4 + pr * 2 + 1;
                            int p = atomicAdd(&qcnt, 1);
                            if (__builtin_expect(p < QMAX, 1)) qlist[p] = (row << 10) | colc;
                            else atomicOr(&ovf, 1u << row);
                        }
                    }
            }
        }
        barrier_lds();

        // ---- exact rescore (sequential-K fp32, reference ordering) ----
        {
            int nc = qcnt < QMAX ? qcnt : QMAX;
            for (int i = tid; i < nc; i += 256) {
                const int rc = qlist[i];
                exact_score(rc >> 10, rc & 1023);
            }
            // repair pass: rows whose candidates overflowed -> full rescan.
            if (__builtin_expect(ovf != 0u, 0)) {
                unsigned om = ovf;
                while (om) {
                    const int row = __ffs(om) - 1;
                    om &= om - 1;
                    for (int c = tid; c < KBINS; c += 256) exact_score(row, c);
                }
            }
        }
        barrier_lds();
        if (tid < RPB) {
            int col = 1023 - (int)(winner[tid] & 1023ull);
            idxs[tid] = col;
            codes_f[(size_t)q * NROWS + r0 + tid] = (float)col;
            rsq[tid] = 0.f;
            ean2_s[tid] = 0.f;
        }
        if (tid == 0) sAg = 0u;
        barrier_lds();

        // ---- update: tmp=c-r; qst=r+tmp; r=r-qst (reference rounding) ----
        {
            const int row = tid & 31, d0 = (tid >> 5) * 32;
            const float* crow = cbq + (size_t)idxs[row] * DDIM + d0;
            float* arow = &As[row][d0];
            float lp = 0.f, pr = 0.f, ma = 0.f;
            #pragma unroll
            for (int u = 0; u < 32; u += 4) {
                const float4 c4 = *(const float4*)(crow + u);
                const float4 a4 = *(const float4*)(arow + u);
                const float cv[4] = { c4.x, c4.y, c4.z, c4.w };
                const float rv[4] = { a4.x, a4.y, a4.z, a4.w };
                float rn[4];
                #pragma unroll
                for (int v = 0; v < 4; ++v) {
                    const float tmp = __fsub_rn(cv[v], rv[v]);
                    const float qs  = __fadd_rn(rv[v], tmp);
                    rn[v] = __fsub_rn(rv[v], qs);
                    lp = __builtin_fmaf(tmp, tmp, lp);
                    pr = __builtin_fmaf(rn[v], rn[v], pr);
                    ma = fmaxf(ma, fabsf(rn[v]));
                }
                float4 o4; o4.x = rn[0]; o4.y = rn[1]; o4.z = rn[2]; o4.w = rn[3];
                *(float4*)(arow + u) = o4;
            }
            atomicAdd(&rsq[row], pr);
            #pragma unroll
            for (int m = 1; m < 64; m <<= 1) {
                lp += __shfl_xor(lp, m, 64);
                ma = fmaxf(ma, __shfl_xor(ma, m, 64));
            }
            if (l == 0) {
                atomicAdd(&loss[q], lp);
                atomicMax(&sAg, __float_as_uint(ma));
            }
        }
        barrier_lds();
    }

    // ---- quantized output: x - final residual (telescoped) ----
    {
        const int row = tid & 31, dg = tid >> 5;
        const int n = r0 + row, b = n / TLEN, t = n % TLEN;
        const float* xp = x + (size_t)b * (DDIM * TLEN) + t;
        float* op = out + (size_t)b * (DDIM * TLEN) + t;
        #pragma unroll
        for (int u = 0; u < 32; ++u) {
            const int d = dg * 32 + u;
            op[(size_t)d * TLEN] = __fsub_rn(xp[(size_t)d * TLEN], As[row][d]);
        }
    }
}

// ---------------------------------------------------------------------------
// Kernel 3: penalty = mean over stages of (loss_q / (N*D))
// ---------------------------------------------------------------------------
__global__ void finalize_kernel(const float* __restrict__ loss, float* __restrict__ out) {
    if (threadIdx.x == 0 && blockIdx.x == 0) {
        float s = 0.f;
        for (int q = 0; q < NQ; ++q) s += loss[q] / (float)(NROWS * DDIM);
        out[(size_t)NBATCH * DDIM * TLEN + (size_t)NQ * NROWS] = s / (float)NQ;
    }
}

extern "C" void kernel_launch(void* const* d_in, const int* in_sizes, int n_in,
                              void* d_out, int out_size, void* d_ws, size_t ws_size,
                              hipStream_t stream) {
    const float* x  = (const float*)d_in[0];
    const float* cb = (const float*)d_in[1];
    float* out  = (float*)d_out;
    float* ws   = (float*)d_ws;
    float* loss = ws + 8208;
    uint4* cbbf = (uint4*)(ws + 24608);               // 131072 uint4 = 2 MB
    const bool wsbf = ws_size >= (size_t)24608 * 4 + (size_t)131072 * 16;

    hipLaunchKernelGGL(table_kernel, dim3((NQ * KBINS) / 256), dim3(256), 0, stream, cb, ws);
    hipLaunchKernelGGL(stagered_kernel, dim3(NQ), dim3(256), 0, stream, ws);
    if (wsbf) {
        hipLaunchKernelGGL(precvt8_kernel, dim3(131072 / 256), dim3(256), 0, stream,
                           cb, ws, cbbf);
        hipLaunchKernelGGL((rvq_kernel<true>), dim3(NROWS / RPB), dim3(256), 0, stream,
                           x, cb, cbbf, ws, loss, out);
    } else {
        hipLaunchKernelGGL((rvq_kernel<false>), dim3(NROWS / RPB), dim3(256), 0, stream,
                           x, cb, cbbf, ws, loss, out);
    }
    hipLaunchKernelGGL(finalize_kernel, dim3(1), dim3(64), 0, stream, loss, out);
}

// Round 13
// 398.772 us; speedup vs baseline: 1.0299x; 1.0299x over previous
//
#include <hip/hip_runtime.h>
#include <math.h>

#define NBATCH 16
#define DDIM   256
#define TLEN   1500
#define NROWS  (NBATCH * TLEN)     // 24000
#define KBINS  1024
#define NQ     8
#define RPB    32                  // rows per block
#define QMAX   512

typedef float f32x4 __attribute__((ext_vector_type(4)));
typedef int   i32x4 __attribute__((ext_vector_type(4)));
union FragI { uint4 u; i32x4 i; };

// LDS-only barrier: waits ds ops, does NOT drain vmcnt -> global prefetch
// stays in flight across phase boundaries. All inter-wave comms here are LDS.
__device__ __forceinline__ void barrier_lds() {
    __builtin_amdgcn_sched_barrier(0);
    asm volatile("s_waitcnt lgkmcnt(0)" ::: "memory");
    __builtin_amdgcn_s_barrier();
    __builtin_amdgcn_sched_barrier(0);
}

// quantize 4 floats to 4 i8 (round-nearest-even), accumulate exact eps^2
__device__ __forceinline__ unsigned pack8(float4 v, float inv, float s, float& e2) {
    float q0 = rintf(v.x * inv), q1 = rintf(v.y * inv);
    float q2 = rintf(v.z * inv), q3 = rintf(v.w * inv);
    float e0 = __builtin_fmaf(-s, q0, v.x), e1 = __builtin_fmaf(-s, q1, v.y);
    float f2 = __builtin_fmaf(-s, q2, v.z), f3 = __builtin_fmaf(-s, q3, v.w);
    e2 += e0 * e0 + e1 * e1 + f2 * f2 + f3 * f3;
    return ((unsigned)((int)q0 & 255)) | (((unsigned)((int)q1 & 255)) << 8)
         | (((unsigned)((int)q2 & 255)) << 16) | (((unsigned)((int)q3 & 255)) << 24);
}

// ws layout (floats):
// [0..8191]      cbsq
// [8192..8207]   stage scalars: q*2+0 = maxabs(cb_q), q*2+1 = max||c||  (plain floats)
// [8208..8215]   loss[8]
// [8224..16415]  eps2col[8192]  (per-col quant eps^2, pure writes)
// [16416..24607] colmax[8192]   (per-col maxabs, pure writes)
// [24608..]      cbbf (131072 uint4 = 2MB)

// ---------------------------------------------------------------------------
// Kernel 1: per-col cbsq (numpy-pairwise) + per-col maxabs. Pure stores,
// NO global atomics. Also zeroes loss.
// ---------------------------------------------------------------------------
__global__ __launch_bounds__(256) void table_kernel(const float* __restrict__ cb,
                                                    float* __restrict__ ws) {
    const int k = blockIdx.x * 256 + threadIdx.x;      // 0..8191
    if (blockIdx.x == 0 && threadIdx.x < NQ) ws[8208 + threadIdx.x] = 0.f;
    if (k >= NQ * KBINS) return;
    const float* p = cb + (size_t)k * DDIM;
    // numpy-pairwise sum(c*c) -- EXACT structure as the passing kernel
    float total = 0.f;
    #pragma unroll
    for (int h = 0; h < 2; ++h) {
        const float* ph = p + h * 128;
        float r[8];
        #pragma unroll
        for (int j = 0; j < 8; ++j) { float v = ph[j]; r[j] = __fmul_rn(v, v); }
        for (int i = 8; i < 128; i += 8) {
            #pragma unroll
            for (int j = 0; j < 8; ++j) {
                float v = ph[i + j];
                r[j] = __fadd_rn(r[j], __fmul_rn(v, v));
            }
        }
        float s = __fadd_rn(__fadd_rn(__fadd_rn(r[0], r[1]), __fadd_rn(r[2], r[3])),
                            __fadd_rn(__fadd_rn(r[4], r[5]), __fadd_rn(r[6], r[7])));
        total = __fadd_rn(total, s);
    }
    ws[k] = total;
    float ma = 0.f;
    for (int i = 0; i < DDIM; i += 4) {
        float4 v = *(const float4*)(p + i);
        ma = fmaxf(ma, fmaxf(fmaxf(fabsf(v.x), fabsf(v.y)), fmaxf(fabsf(v.z), fabsf(v.w))));
    }
    ws[16416 + k] = ma;
}

// ---------------------------------------------------------------------------
// Kernel 1a: per-stage scalars (maxabs, max||c||) via shuffle+LDS reduce.
// One block per stage; single plain store; NO contended atomics.
// ---------------------------------------------------------------------------
__global__ __launch_bounds__(256) void stagered_kernel(float* __restrict__ ws) {
    const int q = blockIdx.x;
    const int tid = threadIdx.x, l = tid & 63, w = tid >> 6;
    __shared__ float redm[4], redc[4];
    float ma = 0.f, cs = 0.f;
    for (int j = tid; j < KBINS; j += 256) {
        ma = fmaxf(ma, ws[16416 + q * KBINS + j]);
        cs = fmaxf(cs, ws[q * KBINS + j]);
    }
    #pragma unroll
    for (int d = 1; d < 64; d <<= 1) {
        ma = fmaxf(ma, __shfl_xor(ma, d, 64));
        cs = fmaxf(cs, __shfl_xor(cs, d, 64));
    }
    if (l == 0) { redm[w] = ma; redc[w] = cs; }
    __syncthreads();
    if (tid == 0) {
        ws[8192 + 2 * q]     = fmaxf(fmaxf(redm[0], redm[1]), fmaxf(redm[2], redm[3]));
        ws[8192 + 2 * q + 1] = sqrtf(fmaxf(fmaxf(redc[0], redc[1]), fmaxf(redc[2], redc[3])));
    }
}

// ---------------------------------------------------------------------------
// Kernel 1b: pre-quantize codebooks fp32 -> i8 (per-stage GLOBAL scale sBq)
// in per-lane MFMA fragment order; per-col eps^2 combined via shfl_xor +
// 16-slot LDS (one block = one (q,ch,w) tile, 4 waves = 4 ks) -> pure store.
// uint4 index J = ((((q*16+ch)*4 + w)*4 + ks)*64 + l); byte p of lane l:
// col = ch*64 + w*16 + (l&15), k = ks*64 + (l>>4)*16 + p  (A uses same k map)
// ---------------------------------------------------------------------------
__global__ __launch_bounds__(256) void precvt8_kernel(const float* __restrict__ cb,
                                                      float* __restrict__ ws,
                                                      uint4* __restrict__ cbbf) {
    __shared__ float e2c[16];
    const int j = blockIdx.x * 256 + threadIdx.x;      // < 131072
    const int l  = j & 63;
    const int ks = (j >> 6) & 3;
    const int w  = (j >> 8) & 3;
    const int ch = (j >> 10) & 15;
    const int q  = j >> 14;
    const int C  = ch * 64 + w * 16 + (l & 15);
    const int g  = l >> 4;
    if (threadIdx.x < 16) e2c[threadIdx.x] = 0.f;
    __syncthreads();
    const float* src = cb + ((size_t)q * KBINS + C) * DDIM + ks * 64 + g * 16;
    const float sB = fmaxf(ws[8192 + 2 * q], 1e-30f) * (1.f / 127.f);
    const float invB = 1.f / sB;
    float e2 = 0.f;
    uint4 o;
    o.x = pack8(*(const float4*)(src + 0),  invB, sB, e2);
    o.y = pack8(*(const float4*)(src + 4),  invB, sB, e2);
    o.z = pack8(*(const float4*)(src + 8),  invB, sB, e2);
    o.w = pack8(*(const float4*)(src + 12), invB, sB, e2);
    cbbf[j] = o;
    e2 += __shfl_xor(e2, 16, 64);
    e2 += __shfl_xor(e2, 32, 64);
    if (l < 16) atomicAdd(&e2c[l], e2);                // LDS atomic, 4 waves only
    __syncthreads();
    if (threadIdx.x < 16)
        ws[8224 + q * KBINS + ch * 64 + w * 16 + threadIdx.x] = e2c[threadIdx.x];
}

// ---------------------------------------------------------------------------
// Kernel 2: residual VQ. i8-MFMA screening, barrier-free monotone cross-wave
// Mpart thresholds (r11, measured-safe), PLUS TEMPORAL PHASE-SKEW: cohort
// (bid>>8) = the co-residency layer on a CU; cohorts 1,2 spin ~10.4/20.8us
// at entry so co-resident blocks occupy DIFFERENT stage sub-phases (screen
// VALU overlaps rescore/staging latency instead of phase-locking). Pure
// delay: zero correctness surface. Screen/threshold/rescore logic is
// byte-equivalent to r11 (rotation reverted; candidate profile proven).
// (256,3): 84-reg cap, 3 blocks/CU, 750 blocks <= 768 slots = one round.
// ---------------------------------------------------------------------------
template<bool WSCB>
__global__ __launch_bounds__(256, 3)
void rvq_kernel(const float* __restrict__ x,
                const float* __restrict__ cb,
                const uint4* __restrict__ cbbf,
                const float* __restrict__ ws,
                float* __restrict__ loss,
                float* __restrict__ out) {
    __shared__ __align__(16) float As[RPB][260];       // residual fp32 (33.3KB)
    __shared__ float cbsqs[KBINS];                     // 4KB
    __shared__ uint4 af_lds[2][4][64];                 // A i8 fragments (8KB)
    __shared__ float rsq[RPB];
    __shared__ float ean2_s[RPB];                      // row quant eps^2
    __shared__ float Mpart[4][RPB];                    // per-wave RUNNING row max
    __shared__ float ebn2_lds[NQ];                     // stage max col eps^2
    __shared__ unsigned long long winner[RPB];
    __shared__ int   idxs[RPB];
    __shared__ int   qlist[QMAX];                      // 2KB
    __shared__ int   qcnt;
    __shared__ unsigned ovf;
    __shared__ unsigned sAg;                           // block max |residual| bits

    const int tid = threadIdx.x;
    const int bid = blockIdx.x;
    const int r0  = bid * RPB;
    const int w   = tid >> 6;          // wave 0..3
    const int l   = tid & 63;
    const int cl  = l & 15;
    const int g   = l >> 4;            // 0..3

    // ---- temporal phase-skew: desync co-resident cohorts (bid, bid+256,
    // bid+512 share a CU). 25K cycles ~ 10.4us ~ 1/5 of a stage. ----
    {
        const long long cohort = (long long)(bid >> 8);    // 0,1,2
        if (cohort > 0) {
            const long long tgt = cohort * 25000;
            long long t0 = clock64();
            while (clock64() - t0 < tgt) {}
        }
    }

    if (tid < RPB) { rsq[tid] = 0.f; ean2_s[tid] = 0.f; }
    if (tid == 0) sAg = 0u;
    barrier_lds();

    // ---- load x (B,D,T) transposed into As[row][d]; ||r||^2 and sAg ----
    {
        const int row = tid & 31, dg = tid >> 5;
        const int n = r0 + row, b = n / TLEN, t = n % TLEN;
        const float* xp = x + (size_t)b * (DDIM * TLEN) + t;
        float pr = 0.f, ma = 0.f;
        #pragma unroll
        for (int dd = 0; dd < DDIM; dd += 8) {
            float v = xp[(size_t)(dd + dg) * TLEN];
            As[row][dd + dg] = v;
            pr = __builtin_fmaf(v, v, pr);
            ma = fmaxf(ma, fabsf(v));
        }
        atomicAdd(&rsq[row], pr);
        #pragma unroll
        for (int d = 1; d < 64; d <<= 1) ma = fmaxf(ma, __shfl_xor(ma, d, 64));
        if (l == 0) atomicMax(&sAg, __float_as_uint(ma));
    }
    // ---- prologue: reduce eps2col -> per-stage max (waves own q, q+4) ----
    if constexpr (WSCB) {
        for (int qq = w; qq < NQ; qq += 4) {
            float m = 0.f;
            for (int j = l; j < KBINS; j += 64)
                m = fmaxf(m, ws[8224 + qq * KBINS + j]);
            #pragma unroll
            for (int d = 1; d < 64; d <<= 1) m = fmaxf(m, __shfl_xor(m, d, 64));
            if (l == 0) ebn2_lds[qq] = m;
        }
    }
    barrier_lds();

    float* codes_f = out + (size_t)NBATCH * DDIM * TLEN;

    uint4 bufA[4], bufB[4];
    float sBq_pf = fmaxf(ws[8192], 1e-30f) * (1.f / 127.f);

    // B-fragment loader: 4 coalesced dwordx4 per chunk (i8, K=64 each)
    auto loadB = [&](uint4 (&buf)[4], int q_, int ch_) {
        if constexpr (WSCB) {
            const uint4* p = cbbf + ((size_t)((q_ * 16 + ch_) * 4 + w) * 4) * 64 + l;
            #pragma unroll
            for (int ks = 0; ks < 4; ++ks) buf[ks] = p[ks * 64];
        } else {
            const int C = ch_ * 64 + w * 16 + cl;
            const float* cp = cb + ((size_t)q_ * KBINS + C) * DDIM;
            const float sB = sBq_pf;
            const float invB = 1.f / sB;
            float dmy = 0.f;
            #pragma unroll
            for (int ks = 0; ks < 4; ++ks) {
                const int d0 = ks * 64 + g * 16;
                buf[ks].x = pack8(*(const float4*)(cp + d0 + 0),  invB, sB, dmy);
                buf[ks].y = pack8(*(const float4*)(cp + d0 + 4),  invB, sB, dmy);
                buf[ks].z = pack8(*(const float4*)(cp + d0 + 8),  invB, sB, dmy);
                buf[ks].w = pack8(*(const float4*)(cp + d0 + 12), invB, sB, dmy);
            }
        }
    };

    loadB(bufA, 0, 0);                 // prologue: stage 0 chunk 0 in flight
    __builtin_amdgcn_sched_barrier(0);

    for (int q = 0; q < NQ; ++q) {
        const float* cbq = cb + (size_t)q * (KBINS * DDIM);

        // ---- per-stage scalars (plain-float reads) ----
        const float sBq = fmaxf(ws[8192 + 2 * q], 1e-30f) * (1.f / 127.f);
        sBq_pf = (q < NQ - 1) ? fmaxf(ws[8192 + 2 * (q + 1)], 1e-30f) * (1.f / 127.f) : sBq;
        const float cnM  = ws[8192 + 2 * q + 1];
        float ebnS;
        if constexpr (WSCB) ebnS = sqrtf(ebn2_lds[q]);
        else                ebnS = 8.f * sBq;          // analytic bound fallback
        const float maxA = fmaxf(__uint_as_float(sAg), 1e-30f);
        const float sA   = maxA * (1.f / 127.f);
        const float invA = 127.f / maxA;
        const float scg  = 2.f * sA * sBq;             // wave-uniform fold scale

        // exact fp32 score of (row,col) -> tournament key -> atomicMax winner
        auto exact_score = [&](int row, int col) {
            const float* cp = cbq + (size_t)col * DDIM;
            const float* ar = As[row];
            float dot = 0.f;
            #pragma unroll 16
            for (int d = 0; d < DDIM; d += 4) {
                float4 c4 = *(const float4*)(cp + d);
                float4 a4 = *(const float4*)(ar + d);
                dot = __builtin_fmaf(a4.x, c4.x, dot);
                dot = __builtin_fmaf(a4.y, c4.y, dot);
                dot = __builtin_fmaf(a4.z, c4.z, dot);
                dot = __builtin_fmaf(a4.w, c4.w, dot);
            }
            float sx = __fsub_rn(__fmul_rn(2.f, dot), cbsqs[col]);
            unsigned ub = __float_as_uint(sx);
            ub = (ub & 0x80000000u) ? ~ub : (ub | 0x80000000u);
            unsigned long long key = ((unsigned long long)ub << 10) | (unsigned)(1023 - col);
            atomicMax(&winner[row], key);
        };

        // ---- stage cbsq into LDS ----
        #pragma unroll
        for (int j = 0; j < 4; ++j)
            cbsqs[tid + j * 256] = ws[q * KBINS + tid + j * 256];

        // ---- A fragments: residual -> i8 into LDS, COOPERATIVE (2/thread) ----
        #pragma unroll
        for (int i = 0; i < 2; ++i) {
            const int f  = tid + 256 * i;              // 0..511
            const int fl = f & 63, fks = (f >> 6) & 3, fmt = f >> 8;
            const int row = fmt * 16 + (fl & 15), gg = fl >> 4;
            const float* ap = &As[row][fks * 64 + gg * 16];
            float e2 = 0.f;
            uint4 o;
            o.x = pack8(*(const float4*)(ap + 0),  invA, sA, e2);
            o.y = pack8(*(const float4*)(ap + 4),  invA, sA, e2);
            o.z = pack8(*(const float4*)(ap + 8),  invA, sA, e2);
            o.w = pack8(*(const float4*)(ap + 12), invA, sA, e2);
            af_lds[fmt][fks][fl] = o;
            atomicAdd(&ean2_s[row], e2);
        }

        if (tid < RPB) winner[tid] = 0ull;
        if (tid < 4 * RPB) ((float*)Mpart)[tid] = -INFINITY;
        if (tid == 0) { qcnt = 0; ovf = 0u; }
        barrier_lds();   // ean2/rsq complete; Mpart init + winner visible

        // ---- per-lane margins (registers; rsq/ean2_s stable post-barrier) ----
        float marg[2][4];
        #pragma unroll
        for (int mt = 0; mt < 2; ++mt)
            #pragma unroll
            for (int jj = 0; jj < 4; ++jj) {
                const int r = mt * 16 + g * 4 + jj;
                marg[mt][jj] = __builtin_fmaf(sqrtf(rsq[r]), ebnS,
                                              sqrtf(ean2_s[r]) * cnM) + 0.25f;
            }

        // ---- BARRIER-FREE screen: monotone cross-wave Mpart thresholds ----
        for (int gi = 0; gi < 8; ++gi) {
            float m_lane[2][4];
            #pragma unroll
            for (int mt = 0; mt < 2; ++mt)
                #pragma unroll
                for (int r = 0; r < 4; ++r) m_lane[mt][r] = -INFINITY;
            unsigned spack[2][2][2];   // 8 VGPRs, static-indexed

            #pragma unroll
            for (int cc = 0; cc < 2; ++cc) {
                const int ch = gi * 2 + cc;
                uint4 (&cur)[4] = (cc & 1) ? bufB : bufA;
                uint4 (&nxt)[4] = (cc & 1) ? bufA : bufB;

                // prefetch next chunk (wraps to next stage's chunk 0)
                int pq = q, pch = ch + 1;
                if (ch == 15) { pq = (q < NQ - 1) ? q + 1 : q; pch = 0; }
                loadB(nxt, pq, pch);
                __builtin_amdgcn_sched_barrier(0);   // pin: loads issue BEFORE MFMAs

                // 8 MFMAs; A streamed from LDS (stride-16B b128)
                i32x4 a0 = {0, 0, 0, 0}, a1 = {0, 0, 0, 0};
                #pragma unroll
                for (int ks = 0; ks < 4; ++ks) {
                    FragI fa0, fa1, b;
                    fa0.u = af_lds[0][ks][l];
                    fa1.u = af_lds[1][ks][l];
                    b.u = cur[ks];
                    a0 = __builtin_amdgcn_mfma_i32_16x16x64_i8(fa0.i, b.i, a0, 0, 0, 0);
                    a1 = __builtin_amdgcn_mfma_i32_16x16x64_i8(fa1.i, b.i, a1, 0, 0, 0);
                }

                // fold: s = scg*idot - cbsq; running max; truncate-pack
                const float cq = cbsqs[ch * 64 + w * 16 + cl];
                {
                    float s0 = __builtin_fmaf(scg, (float)a0[0], -cq);
                    float s1 = __builtin_fmaf(scg, (float)a0[1], -cq);
                    float s2 = __builtin_fmaf(scg, (float)a0[2], -cq);
                    float s3 = __builtin_fmaf(scg, (float)a0[3], -cq);
                    m_lane[0][0] = fmaxf(m_lane[0][0], s0);
                    m_lane[0][1] = fmaxf(m_lane[0][1], s1);
                    m_lane[0][2] = fmaxf(m_lane[0][2], s2);
                    m_lane[0][3] = fmaxf(m_lane[0][3], s3);
                    spack[cc][0][0] = (__float_as_uint(s1) & 0xFFFF0000u) | (__float_as_uint(s0) >> 16);
                    spack[cc][0][1] = (__float_as_uint(s3) & 0xFFFF0000u) | (__float_as_uint(s2) >> 16);
                }
                {
                    float s0 = __builtin_fmaf(scg, (float)a1[0], -cq);
                    float s1 = __builtin_fmaf(scg, (float)a1[1], -cq);
                    float s2 = __builtin_fmaf(scg, (float)a1[2], -cq);
                    float s3 = __builtin_fmaf(scg, (float)a1[3], -cq);
                    m_lane[1][0] = fmaxf(m_lane[1][0], s0);
                    m_lane[1][1] = fmaxf(m_lane[1][1], s1);
                    m_lane[1][2] = fmaxf(m_lane[1][2], s2);
                    m_lane[1][3] = fmaxf(m_lane[1][3], s3);
                    spack[cc][1][0] = (__float_as_uint(s1) & 0xFFFF0000u) | (__float_as_uint(s0) >> 16);
                    spack[cc][1][1] = (__float_as_uint(s3) & 0xFFFF0000u) | (__float_as_uint(s2) >> 16);
                }
            }

            // ---- reduce group maxima over the 16-col group (intra-wave) ----
            #pragma unroll
            for (int m = 1; m <= 8; m <<= 1)
                #pragma unroll
                for (int mt = 0; mt < 2; ++mt)
                    #pragma unroll
                    for (int r = 0; r < 4; ++r)
                        m_lane[mt][r] = fmaxf(m_lane[mt][r], __shfl_xor(m_lane[mt][r], m, 64));

            // ---- publish own wave's running max (monotone, no barrier) ----
            if (cl == 0) {
                #pragma unroll
                for (int mt = 0; mt < 2; ++mt)
                    #pragma unroll
                    for (int r = 0; r < 4; ++r) {
                        const int rr = mt * 16 + g * 4 + r;
                        Mpart[w][rr] = fmaxf(Mpart[w][rr], m_lane[mt][r]);
                    }
            }

            // ---- thresholds: racy cross-wave max (stale = lower bound, safe) ----
            float thrl[2][4];
            #pragma unroll
            for (int mt = 0; mt < 2; ++mt)
                #pragma unroll
                for (int jj = 0; jj < 4; ++jj) {
                    const int rr = mt * 16 + g * 4 + jj;
                    float Mr = fmaxf(fmaxf(Mpart[0][rr], Mpart[1][rr]),
                                     fmaxf(Mpart[2][rr], Mpart[3][rr]));
                    Mr = fmaxf(Mr, m_lane[mt][jj]);    // own group, provably current
                    thrl[mt][jj] = Mr - (marg[mt][jj] + 0.006f * fabsf(Mr));
                }

            // ---- scan the group's 2 chunks of packed scores ----
            #pragma unroll
            for (int cc = 0; cc < 2; ++cc) {
                const int colc = (gi * 2 + cc) * 64 + w * 16 + cl;
                #pragma unroll
                for (int mt = 0; mt < 2; ++mt)
                    #pragma unroll
                    for (int pr = 0; pr < 2; ++pr) {
                        unsigned u = spack[cc][mt][pr];
                        float slo = __uint_as_float(u << 16);
                        float shi = __uint_as_float(u & 0xFFFF0000u);
                        if (slo >= thrl[mt][pr * 2]) {
                            const int row = mt * 16 + g * 4 + pr * 2;
                            int p = atomicAdd(&qcnt, 1);
                            if (__builtin_expect(p < QMAX, 1)) qlist[p] = (row << 10) | colc;
                            else atomicOr(&ovf, 1u << row);
                        }
                        if (shi >= thrl[mt][pr * 2 + 1]) {
                            const int row = mt * 16 + g * 4 + pr * 2 + 1;
                            int p = atomicAdd(&qcnt, 1);
                            if (__builtin_expect(p < QMAX, 1)) qlist[p] = (row << 10) | colc;
                            else atomicOr(&ovf, 1u << row);
                        }
                    }
            }
        }
        barrier_lds();

        // ---- exact rescore (sequential-K fp32, reference ordering) ----
        {
            int nc = qcnt < QMAX ? qcnt : QMAX;
            for (int i = tid; i < nc; i += 256) {
                const int rc = qlist[i];
                exact_score(rc >> 10, rc & 1023);
            }
            // repair pass: rows whose candidates overflowed -> full rescan.
            if (__builtin_expect(ovf != 0u, 0)) {
                unsigned om = ovf;
                while (om) {
                    const int row = __ffs(om) - 1;
                    om &= om - 1;
                    for (int c = tid; c < KBINS; c += 256) exact_score(row, c);
                }
            }
        }
        barrier_lds();
        if (tid < RPB) {
            int col = 1023 - (int)(winner[tid] & 1023ull);
            idxs[tid] = col;
            codes_f[(size_t)q * NROWS + r0 + tid] = (float)col;
            rsq[tid] = 0.f;
            ean2_s[tid] = 0.f;
        }
        if (tid == 0) sAg = 0u;
        barrier_lds();

        // ---- update: tmp=c-r; qst=r+tmp; r=r-qst (reference rounding) ----
        {
            const int row = tid & 31, d0 = (tid >> 5) * 32;
            const float* crow = cbq + (size_t)idxs[row] * DDIM + d0;
            float* arow = &As[row][d0];
            float lp = 0.f, pr = 0.f, ma = 0.f;
            #pragma unroll
            for (int u = 0; u < 32; u += 4) {
                const float4 c4 = *(const float4*)(crow + u);
                const float4 a4 = *(const float4*)(arow + u);
                const float cv[4] = { c4.x, c4.y, c4.z, c4.w };
                const float rv[4] = { a4.x, a4.y, a4.z, a4.w };
                float rn[4];
                #pragma unroll
                for (int v = 0; v < 4; ++v) {
                    const float tmp = __fsub_rn(cv[v], rv[v]);
                    const float qs  = __fadd_rn(rv[v], tmp);
                    rn[v] = __fsub_rn(rv[v], qs);
                    lp = __builtin_fmaf(tmp, tmp, lp);
                    pr = __builtin_fmaf(rn[v], rn[v], pr);
                    ma = fmaxf(ma, fabsf(rn[v]));
                }
                float4 o4; o4.x = rn[0]; o4.y = rn[1]; o4.z = rn[2]; o4.w = rn[3];
                *(float4*)(arow + u) = o4;
            }
            atomicAdd(&rsq[row], pr);
            #pragma unroll
            for (int m = 1; m < 64; m <<= 1) {
                lp += __shfl_xor(lp, m, 64);
                ma = fmaxf(ma, __shfl_xor(ma, m, 64));
            }
            if (l == 0) {
                atomicAdd(&loss[q], lp);
                atomicMax(&sAg, __float_as_uint(ma));
            }
        }
        barrier_lds();
    }

    // ---- quantized output: x - final residual (telescoped) ----
    {
        const int row = tid & 31, dg = tid >> 5;
        const int n = r0 + row, b = n / TLEN, t = n % TLEN;
        const float* xp = x + (size_t)b * (DDIM * TLEN) + t;
        float* op = out + (size_t)b * (DDIM * TLEN) + t;
        #pragma unroll
        for (int u = 0; u < 32; ++u) {
            const int d = dg * 32 + u;
            op[(size_t)d * TLEN] = __fsub_rn(xp[(size_t)d * TLEN], As[row][d]);
        }
    }
}

// ---------------------------------------------------------------------------
// Kernel 3: penalty = mean over stages of (loss_q / (N*D))
// ---------------------------------------------------------------------------
__global__ void finalize_kernel(const float* __restrict__ loss, float* __restrict__ out) {
    if (threadIdx.x == 0 && blockIdx.x == 0) {
        float s = 0.f;
        for (int q = 0; q < NQ; ++q) s += loss[q] / (float)(NROWS * DDIM);
        out[(size_t)NBATCH * DDIM * TLEN + (size_t)NQ * NROWS] = s / (float)NQ;
    }
}

extern "C" void kernel_launch(void* const* d_in, const int* in_sizes, int n_in,
                              void* d_out, int out_size, void* d_ws, size_t ws_size,
                              hipStream_t stream) {
    const float* x  = (const float*)d_in[0];
    const float* cb = (const float*)d_in[1];
    float* out  = (float*)d_out;
    float* ws   = (float*)d_ws;
    float* loss = ws + 8208;
    uint4* cbbf = (uint4*)(ws + 24608);               // 131072 uint4 = 2 MB
    const bool wsbf = ws_size >= (size_t)24608 * 4 + (size_t)131072 * 16;

    hipLaunchKernelGGL(table_kernel, dim3((NQ * KBINS) / 256), dim3(256), 0, stream, cb, ws);
    hipLaunchKernelGGL(stagered_kernel, dim3(NQ), dim3(256), 0, stream, ws);
    if (wsbf) {
        hipLaunchKernelGGL(precvt8_kernel, dim3(131072 / 256), dim3(256), 0, stream,
                           cb, ws, cbbf);
        hipLaunchKernelGGL((rvq_kernel<true>), dim3(NROWS / RPB), dim3(256), 0, stream,
                           x, cb, cbbf, ws, loss, out);
    } else {
        hipLaunchKernelGGL((rvq_kernel<false>), dim3(NROWS / RPB), dim3(256), 0, stream,
                           x, cb, cbbf, ws, loss, out);
    }
    hipLaunchKernelGGL(finalize_kernel, dim3(1), dim3(64), 0, stream, loss, out);
}